// Round 12
// baseline (596.447 us; speedup 1.0000x reference)
//
#include <hip/hip_runtime.h>

// GraphSAGE 2-layer. N=40000, E=640000, 128 -> 512 (relu) -> 256.
// Round 19: launch-chain collapse. Round-18 reverted (agg1-in-GEMM put the
// gather at every block's head with only 2 resident blocks -> 88.7 us).
// Round-17 state: kernels sum to ~170 us but wall = 274.5 -> ~100 us is
// 8 serial dispatch boundaries. Fix: scanA/scanB/scanC/fill/agg1 -> ONE
// kernel with a hand-rolled sense-reversing grid barrier (device atomics).
// Deadlock-safe by construction: 1024 blocks x 256 thr = 4 blocks/CU =
// 16 waves/CU, __launch_bounds__(256,4) caps VGPR at 128 (actual ~40),
// LDS 3 KB -> all blocks co-resident. Chain: memset -> prep -> csr_agg1
// -> gemm_fused(round-17 BM=64) -> agg2. 5 nodes vs 9.

#define N_NODES 40000
#define N_EDGES 640000
#define F_IN 128
#define F_HID 512
#define F_OUT 256
#define NB_SCAN 157   // ceil(40000/256)
#define G_CSR 1024    // co-resident by construction (4 blocks/CU)

typedef unsigned short ushort_t;
typedef __attribute__((ext_vector_type(8))) short bf16x8;
typedef __attribute__((ext_vector_type(4))) float floatx4;

__device__ __forceinline__ ushort_t f2bf(float f) {
  union { float f; unsigned int u; } x; x.f = f;
  unsigned int r = (x.u + 0x7FFFu + ((x.u >> 16) & 1u)) >> 16;  // RNE
  return (ushort_t)r;
}
__device__ __forceinline__ float bf2f(ushort_t u) {
  union { unsigned int u; float f; } x; x.u = ((unsigned int)u) << 16;
  return x.f;
}

// sense-reversing grid barrier: cnt/gen in workspace, zeroed per launch.
__device__ __forceinline__ void grid_bar(int* cnt, int* gen) {
  __syncthreads();
  if (threadIdx.x == 0) {
    __threadfence();
    int g = atomicAdd(gen, 0);             // current generation
    int v = atomicAdd(cnt, 1);
    if (v == G_CSR - 1) {
      atomicExch(cnt, 0);                  // reset before release
      __threadfence();
      atomicAdd(gen, 1);                   // release spinners
    } else {
      while (atomicAdd(gen, 0) == g) __builtin_amdgcn_s_sleep(2);
    }
    __threadfence();
  }
  __syncthreads();
}

// ---------------- fused preprocessing ----------------
// Wp pack: element (n_global = rowoff+n, k_global = koff+k) at
//   Wp[((gg*(KT/32) + t)*4 + ni)*512 + (qk*16 + lm)*8 + j]
// gg=n>>6, ni=(n>>4)&3, lm=n&15, c=kg>>3, j=kg&7, t=c>>2, qk=c&3.
__device__ __forceinline__ void wp_body(const float* __restrict__ W,
                                        ushort_t* __restrict__ Wp,
                                        int i, int K, int N, int rowoff, int koff,
                                        int KT) {
  if (i < K * N) {
    int n = i / K, k = i - n * K;
    int ng = rowoff + n, kg = koff + k;
    int gg = ng >> 6, ni = (ng >> 4) & 3, lm = ng & 15;
    int c = kg >> 3, j = kg & 7, t = c >> 2, qk = c & 3;
    size_t dst = (((size_t)(gg * (KT / 32) + t) * 4 + ni) * 64 + qk * 16 + lm) * 8 + j;
    Wp[dst] = f2bf(W[(size_t)k * N + n]);
  }
}

// block ranges: [0,5000) cvt_x | [5000,5256) W1l | [5256,5512) W1r
// [5512,6024) W2l | [6024,6536) W2r | [6536,6538) biascat | [6538,9038) deg
#define PREP_BLOCKS 9038
__global__ void prep_kernel(const float* __restrict__ x, ushort_t* __restrict__ xb,
                            const float* __restrict__ W1l, const float* __restrict__ W1r,
                            const float* __restrict__ W2l, const float* __restrict__ W2r,
                            ushort_t* __restrict__ Wp1, ushort_t* __restrict__ Wp2,
                            const float* __restrict__ b2, float* __restrict__ bc,
                            const int* __restrict__ ei, int* __restrict__ deg) {
  int b = blockIdx.x, tid = threadIdx.x;
  if (b < 5000) {
    int i = b * 256 + tid;  // per float4
    const int n4 = (N_NODES * F_IN) / 4;
    if (i < n4) {
      float4 v = ((const float4*)x)[i];
      ushort4 o;
      o.x = f2bf(v.x); o.y = f2bf(v.y); o.z = f2bf(v.z); o.w = f2bf(v.w);
      ((ushort4*)xb)[i] = o;
    }
  } else if (b < 5256) {
    wp_body(W1l, Wp1, (b - 5000) * 256 + tid, 128, 512, 0, 0, 256);
  } else if (b < 5512) {
    wp_body(W1r, Wp1, (b - 5256) * 256 + tid, 128, 512, 0, 128, 256);
  } else if (b < 6024) {
    wp_body(W2l, Wp2, (b - 5512) * 256 + tid, 512, 256, 0, 0, 512);
  } else if (b < 6536) {
    wp_body(W2r, Wp2, (b - 6024) * 256 + tid, 512, 256, 256, 0, 512);
  } else if (b < 6538) {
    int i = (b - 6536) * 256 + tid;
    if (i < 512) bc[i] = (i < 256) ? 0.f : b2[i - 256];
  } else {
    int e = (b - 6538) * 256 + tid;
    if (e < N_EDGES) atomicAdd(&deg[ei[N_EDGES + e]], 1);
  }
}

// ---------------- CSR build + agg1, single kernel, grid barriers ----------
__global__ __launch_bounds__(256, 4) void csr_agg1_kernel(
    const int* __restrict__ deg, int* __restrict__ bsum, int* __restrict__ boff,
    int* __restrict__ rowptr, int* __restrict__ cursor,
    const int* __restrict__ ei, int* __restrict__ col,
    const ushort_t* __restrict__ Xb, ushort_t* __restrict__ Yb,
    int* bar_cnt, int* bar_gen) {
  const int bid = blockIdx.x, tid = threadIdx.x;
  __shared__ int sdata[256];
  __shared__ int buf[2][256];

  // ---- phase A: per-tile sums of deg ----
  for (int t = bid; t < NB_SCAN; t += G_CSR) {
    int i = t * 256 + tid;
    sdata[tid] = (i < N_NODES) ? deg[i] : 0;
    __syncthreads();
    #pragma unroll
    for (int off = 128; off > 0; off >>= 1) {
      if (tid < off) sdata[tid] += sdata[tid + off];
      __syncthreads();
    }
    if (tid == 0) bsum[t] = sdata[0];
    __syncthreads();
  }
  grid_bar(bar_cnt, bar_gen);

  // ---- phase B: exclusive scan of 157 tile sums (block 0) ----
  if (bid == 0) {
    int v = (tid < NB_SCAN) ? bsum[tid] : 0;
    buf[0][tid] = v;
    __syncthreads();
    int cur = 0;
    #pragma unroll
    for (int off = 1; off < 256; off <<= 1) {
      int val = buf[cur][tid];
      if (tid >= off) val += buf[cur][tid - off];
      buf[cur ^ 1][tid] = val;
      __syncthreads();
      cur ^= 1;
    }
    if (tid < NB_SCAN) boff[tid] = buf[cur][tid] - v;  // exclusive
  }
  grid_bar(bar_cnt, bar_gen);

  // ---- phase C: rowptr + cursor ----
  for (int t = bid; t < NB_SCAN; t += G_CSR) {
    int i = t * 256 + tid;
    int v = (i < N_NODES) ? deg[i] : 0;
    buf[0][tid] = v;
    __syncthreads();
    int cur = 0;
    #pragma unroll
    for (int off = 1; off < 256; off <<= 1) {
      int val = buf[cur][tid];
      if (tid >= off) val += buf[cur][tid - off];
      buf[cur ^ 1][tid] = val;
      __syncthreads();
      cur ^= 1;
    }
    if (i < N_NODES) {
      int ex = boff[t] + buf[cur][tid] - v;
      rowptr[i] = ex;
      cursor[i] = ex;
      if (i == N_NODES - 1) rowptr[N_NODES] = ex + v;  // == E
    }
    __syncthreads();
  }
  grid_bar(bar_cnt, bar_gen);

  // ---- phase D: fill col ----
  for (int e = bid * 256 + tid; e < N_EDGES; e += G_CSR * 256) {
    int d = ei[N_EDGES + e];
    int s = ei[e];
    int pos = atomicAdd(&cursor[d], 1);
    col[pos] = s;
  }
  grid_bar(bar_cnt, bar_gen);

  // ---- phase E: agg1 (wave = node, readlane gather, 8 in flight) ----
  const int wave = tid >> 6, lane = tid & 63;
  for (int n = bid * 4 + wave; n < N_NODES; n += G_CSR * 4) {
    const int s = rowptr[n], e = rowptr[n + 1];
    float s0 = 0.f, s1 = 0.f;
    for (int base = s; base < e; base += 64) {
      int cnt = min(64, e - base);
      int c = (base + lane < e) ? col[base + lane] : 0;  // coalesced
      int j = 0;
      for (; j + 8 <= cnt; j += 8) {
        unsigned int v[8];
        #pragma unroll
        for (int u = 0; u < 8; ++u) {
          int cc = __builtin_amdgcn_readlane(c, j + u);
          v[u] = *(const unsigned int*)(Xb + (size_t)cc * F_IN + 2 * lane);
        }
        #pragma unroll
        for (int u = 0; u < 8; ++u) {
          s0 += bf2f((ushort_t)(v[u] & 0xffffu));
          s1 += bf2f((ushort_t)(v[u] >> 16));
        }
      }
      for (; j < cnt; ++j) {
        int cc = __builtin_amdgcn_readlane(c, j);
        unsigned int v = *(const unsigned int*)(Xb + (size_t)cc * F_IN + 2 * lane);
        s0 += bf2f((ushort_t)(v & 0xffffu));
        s1 += bf2f((ushort_t)(v >> 16));
      }
    }
    float inv = 1.f / fmaxf((float)(e - s), 1.f);
    unsigned int o = (unsigned int)f2bf(s0 * inv) |
                     ((unsigned int)f2bf(s1 * inv) << 16);
    *(unsigned int*)(Yb + (size_t)n * F_IN + 2 * lane) = o;
  }
}

// ---------------- aggregation (layer 2) ----------------
__global__ void agg2_kernel(const ushort_t* __restrict__ hl, const float* __restrict__ hr,
                            float* __restrict__ out,
                            const int* __restrict__ rowptr, const int* __restrict__ colidx) {
  __shared__ int cols[128];
  int n = blockIdx.x, f = threadIdx.x;
  int s = rowptr[n], e = rowptr[n + 1];
  float2 hrv = *(const float2*)(hr + (size_t)n * F_OUT + 2 * f);  // hoisted stream
  float s0 = 0.f, s1 = 0.f;
  for (int base = s; base < e; base += 128) {
    int cnt = min(128, e - base);
    __syncthreads();
    if (f < cnt) cols[f] = colidx[base + f];
    __syncthreads();
    int j = 0;
    for (; j + 8 <= cnt; j += 8) {  // 8 gathers in flight
      unsigned int v[8];
      #pragma unroll
      for (int u = 0; u < 8; ++u)
        v[u] = *(const unsigned int*)(hl + (size_t)cols[j + u] * F_OUT + 2 * f);
      #pragma unroll
      for (int u = 0; u < 8; ++u) {
        s0 += bf2f((ushort_t)(v[u] & 0xffffu));
        s1 += bf2f((ushort_t)(v[u] >> 16));
      }
    }
    for (; j < cnt; ++j) {
      unsigned int v = *(const unsigned int*)(hl + (size_t)cols[j] * F_OUT + 2 * f);
      s0 += bf2f((ushort_t)(v & 0xffffu));
      s1 += bf2f((ushort_t)(v >> 16));
    }
  }
  float inv = 1.f / fmaxf((float)(e - s), 1.f);
  float2 o;
  o.x = s0 * inv + hrv.x;
  o.y = s1 * inv + hrv.y;
  *(float2*)(out + (size_t)n * F_OUT + 2 * f) = o;
}

// ---------------- fused two-layer bf16 MFMA GEMM, BM=64, aliased LDS ----
// (round-17 kernel, unchanged) Per 64-row M-tile (grid 625, 512 thr/8 waves,
// wave w owns cols w*64..w*64+63): stage [aggx|x] -> Pan (swizzled);
// K-loop1 (KT=256) -> acc1; barrier; relu+bias -> bf16 -> Pan; barrier;
// K-loop2 (KT=512, A=Pan) -> acc2; split epilogue. LDS 64 KB aliased.
__device__ __forceinline__ void mm64(const ushort_t* Pan, int k, int qk, int lm,
                                     bf16x8 f0, bf16x8 f1, bf16x8 f2, bf16x8 f3,
                                     floatx4 (&acc)[4][4]) {
  const int kc = k / 8 + qk;
  #pragma unroll
  for (int mi = 0; mi < 4; ++mi) {
    size_t o = ((size_t)(kc * 64 + mi * 16 + lm) * 16) ^ (size_t)((kc & 7) << 4);
    bf16x8 av = *(const bf16x8*)((const char*)Pan + o);
    acc[mi][0] = __builtin_amdgcn_mfma_f32_16x16x32_bf16(f0, av, acc[mi][0], 0, 0, 0);
    acc[mi][1] = __builtin_amdgcn_mfma_f32_16x16x32_bf16(f1, av, acc[mi][1], 0, 0, 0);
    acc[mi][2] = __builtin_amdgcn_mfma_f32_16x16x32_bf16(f2, av, acc[mi][2], 0, 0, 0);
    acc[mi][3] = __builtin_amdgcn_mfma_f32_16x16x32_bf16(f3, av, acc[mi][3], 0, 0, 0);
  }
}

__global__ __launch_bounds__(512) void gemm_fused(
    const ushort_t* __restrict__ A0,   // aggx  [40000][128]
    const ushort_t* __restrict__ A1,   // x     [40000][128]
    const ushort_t* __restrict__ Wp1,  // packed layer-1 weights (KT=256)
    const float* __restrict__ b1,
    const ushort_t* __restrict__ Wp2,  // packed layer-2 weights (KT=512)
    const float* __restrict__ bc,      // [0 | b2]
    float* __restrict__ hr, ushort_t* __restrict__ hl) {
  __shared__ ushort_t Pan[64 * 512];   // 64 KB: A panel (first 32 KB), then H
  const int tid = threadIdx.x;
  const int wave = tid >> 6, lane = tid & 63;
  const int lm = lane & 15, qk = lane >> 4;
  const int bm = blockIdx.x * 64;      // 625 * 64 = 40000, no tail

  const ushort_t* wpg1 = Wp1 + (size_t)wave * 8 * 2048;   // (256/32) t-blocks
  const ushort_t* wpg2 = Wp2 + (size_t)wave * 16 * 2048;  // (512/32) t-blocks
#define LDB1(t, ni) (*(const bf16x8*)(wpg1 + ((size_t)(t) * 4 + (ni)) * 512 + lane * 8))
#define LDB2(t, ni) (*(const bf16x8*)(wpg2 + ((size_t)(t) * 4 + (ni)) * 512 + lane * 8))

  // ---- stage [aggx|x] panel: 64 rows x 32 chunks, 4 chunks per thread ----
  #pragma unroll
  for (int q = 0; q < 4; ++q) {
    int c = tid + q * 512;
    int lc = c & 31;              // chunk (k / 8)
    int row = c >> 5;             // 0..63
    const ushort_t* src = (lc >= 16)
        ? A1 + (size_t)(bm + row) * 128 + (lc - 16) * 8
        : A0 + (size_t)(bm + row) * 128 + lc * 8;
    bf16x8 v = *(const bf16x8*)src;
    size_t off = ((size_t)(lc * 64 + row) * 16) ^ (size_t)((lc & 7) << 4);
    *(bf16x8*)((char*)Pan + off) = v;
  }

  bf16x8 bvA[4], bvB[4];
  #pragma unroll
  for (int ni = 0; ni < 4; ++ni) bvA[ni] = LDB1(0, ni);
  __syncthreads();  // barrier 1: A panel visible

  // ---- K-loop 1 (KT = 256) ----
  floatx4 acc1[4][4] = {};
  #pragma unroll 1
  for (int kb = 0; kb < 256; kb += 64) {
    const int t0 = kb / 32;
    #pragma unroll
    for (int ni = 0; ni < 4; ++ni) bvB[ni] = LDB1(t0 + 1, ni);
    mm64(Pan, kb, qk, lm, bvA[0], bvA[1], bvA[2], bvA[3], acc1);
    if (kb + 64 < 256) {
      #pragma unroll
      for (int ni = 0; ni < 4; ++ni) bvA[ni] = LDB1(t0 + 2, ni);
    }
    mm64(Pan, kb + 32, qk, lm, bvB[0], bvB[1], bvB[2], bvB[3], acc1);
  }

  #pragma unroll
  for (int ni = 0; ni < 4; ++ni) bvA[ni] = LDB2(0, ni);  // issue before barriers
  __syncthreads();  // barrier 2: all waves done READING A before H overwrites

  // ---- epilogue 1: relu(acc1 + b1) -> bf16 -> Pan (swizzled, full 64 KB) ----
  #pragma unroll
  for (int ni = 0; ni < 4; ++ni) {
    int colg = wave * 64 + ni * 16 + qk * 4;
    float4 b4 = *(const float4*)&b1[colg];
    int lc2 = colg >> 3;
    int sub = (qk & 1) * 8;  // byte offset within the 16-B chunk
    #pragma unroll
    for (int mi = 0; mi < 4; ++mi) {
      int row = mi * 16 + lm;
      ushort4 o;
      o.x = f2bf(fmaxf(acc1[mi][ni][0] + b4.x, 0.f));
      o.y = f2bf(fmaxf(acc1[mi][ni][1] + b4.y, 0.f));
      o.z = f2bf(fmaxf(acc1[mi][ni][2] + b4.z, 0.f));
      o.w = f2bf(fmaxf(acc1[mi][ni][3] + b4.w, 0.f));
      size_t off = (((size_t)(lc2 * 64 + row) * 16) ^ (size_t)((lc2 & 7) << 4)) + sub;
      *(ushort4*)((char*)Pan + off) = o;
    }
  }
  __syncthreads();  // barrier 3: H panel visible

  // ---- K-loop 2 (KT = 512, A = Pan) ----
  floatx4 acc2[4][4] = {};
  #pragma unroll 1
  for (int kb = 0; kb < 512; kb += 64) {
    const int t0 = kb / 32;
    #pragma unroll
    for (int ni = 0; ni < 4; ++ni) bvB[ni] = LDB2(t0 + 1, ni);
    mm64(Pan, kb, qk, lm, bvA[0], bvA[1], bvA[2], bvA[3], acc2);
    if (kb + 64 < 512) {
      #pragma unroll
      for (int ni = 0; ni < 4; ++ni) bvA[ni] = LDB2(t0 + 2, ni);
    }
    mm64(Pan, kb + 32, qk, lm, bvB[0], bvB[1], bvB[2], bvB[3], acc2);
  }
#undef LDB1
#undef LDB2

  // ---- epilogue 2: cols<256 -> hl bf16, cols>=256 -> hr fp32 ----
  #pragma unroll
  for (int ni = 0; ni < 4; ++ni) {
    int colg = wave * 64 + ni * 16 + qk * 4;
    float4 b4 = *(const float4*)&bc[colg];
    #pragma unroll
    for (int mi = 0; mi < 4; ++mi) {
      int rowg = bm + mi * 16 + lm;
      float v0 = acc2[mi][ni][0] + b4.x;
      float v1 = acc2[mi][ni][1] + b4.y;
      float v2 = acc2[mi][ni][2] + b4.z;
      float v3 = acc2[mi][ni][3] + b4.w;
      if (colg < 256) {
        ushort4 o = {f2bf(v0), f2bf(v1), f2bf(v2), f2bf(v3)};
        *(ushort4*)&hl[(size_t)rowg * 256 + colg] = o;
      } else {
        float4 o = {v0, v1, v2, v3};
        *(float4*)&hr[(size_t)rowg * 256 + (colg - 256)] = o;
      }
    }
  }
}

extern "C" void kernel_launch(void* const* d_in, const int* in_sizes, int n_in,
                              void* d_out, int out_size, void* d_ws, size_t ws_size,
                              hipStream_t stream) {
  const float* x = (const float*)d_in[0];
  const int* ei = (const int*)d_in[1];  // int32 per harness, [2][E]
  const float* W1l = (const float*)d_in[2];
  const float* b1 = (const float*)d_in[3];
  const float* W1r = (const float*)d_in[4];
  const float* W2l = (const float*)d_in[5];
  const float* b2 = (const float*)d_in[6];
  const float* W2r = (const float*)d_in[7];
  float* out = (float*)d_out;

  char* ws = (char*)d_ws;
  size_t off = 0;
  auto alloc = [&](size_t bytes) {
    void* p = ws + off;
    off = (off + bytes + 255) & ~(size_t)255;
    return p;
  };
  int* deg = (int*)alloc((size_t)(N_NODES + 64) * 4);  // deg + barrier vars
  int* bar_cnt = deg + N_NODES;      // zeroed together with deg
  int* bar_gen = deg + N_NODES + 1;
  int* rowptr = (int*)alloc((size_t)(N_NODES + 1) * 4);
  int* cursor = (int*)alloc((size_t)N_NODES * 4);
  int* col = (int*)alloc((size_t)N_EDGES * 4);
  int* bsum = (int*)alloc((size_t)NB_SCAN * 4);
  int* boff = (int*)alloc((size_t)NB_SCAN * 4);
  ushort_t* x_bf = (ushort_t*)alloc((size_t)N_NODES * F_IN * 2);
  ushort_t* aggx_bf = (ushort_t*)alloc((size_t)N_NODES * F_IN * 2);
  ushort_t* hl_bf = (ushort_t*)alloc((size_t)N_NODES * F_OUT * 2);  // h@W2l, bf16
  float* hr = (float*)alloc((size_t)N_NODES * F_OUT * 4);           // h@W2r + b2
  ushort_t* Wp1 = (ushort_t*)alloc((size_t)512 * 256 * 2);   // packed [W1l^T|W1r^T]
  ushort_t* Wp2 = (ushort_t*)alloc((size_t)512 * 512 * 2);   // packed [W2l|W2r]
  float* biascat = (float*)alloc(512 * 4);

  // Zero deg + barrier vars in one memset
  hipMemsetAsync(deg, 0, (size_t)(N_NODES + 64) * 4, stream);

  // Fused preprocessing: cvt_x + 4x wp + biascat + deg (independent work)
  prep_kernel<<<PREP_BLOCKS, 256, 0, stream>>>(
      x, x_bf, W1l, W1r, W2l, W2r, Wp1, Wp2, b2, biascat, ei, deg);

  // CSR build + agg1, one kernel with grid barriers
  csr_agg1_kernel<<<G_CSR, 256, 0, stream>>>(
      deg, bsum, boff, rowptr, cursor, ei, col, x_bf, aggx_bf,
      bar_cnt, bar_gen);

  // Fused [layer1 GEMM -> LDS -> layer2 GEMM]
  gemm_fused<<<625, 512, 0, stream>>>(
      aggx_bf, x_bf, Wp1, b1, Wp2, biascat, hr, hl_bf);
  // out = mean-agg(hl_bf) + hr
  agg2_kernel<<<N_NODES, 128, 0, stream>>>(hl_bf, hr, out, rowptr, col);
}

// Round 13
// 578.513 us; speedup vs baseline: 1.0310x; 1.0310x over previous
//
#include <hip/hip_runtime.h>

// GraphSAGE 2-layer. N=40000, E=640000, 128 -> 512 (relu) -> 256.
// Round 20: clean launch-gap test. Round-19 reverted -- its 400 us was
// agg1's TLP collapsing 10x inside the 1024-block cooperative grid
// (latency-bound gathers scale with wave count), NOT barrier cost; the
// launch-gap theory was never actually tested. This round: round-17
// config restored (274.5 us best), and ONLY the four small TLP-light
// kernels (scanA/scanB/scanC/fill) merge into one cooperative kernel
// with 3 grid barriers (read-only __hip_atomic_load polling; 1024 blocks
// x 256 thr, VGPR~40/LDS 3KB -> 8 blocks/CU capacity >= 4 needed, all
// co-resident by construction). agg1 stays standalone at 10000 blocks
// (full TLP). Chain: memset->prep->csr_fill->agg1->gemm_fused->agg2
// (6 nodes vs 9). If gain < 8 us, launch-gap theory is dead.

#define N_NODES 40000
#define N_EDGES 640000
#define F_IN 128
#define F_HID 512
#define F_OUT 256
#define NB_SCAN 157   // ceil(40000/256)
#define G_CSR 1024    // co-resident by construction

typedef unsigned short ushort_t;
typedef __attribute__((ext_vector_type(8))) short bf16x8;
typedef __attribute__((ext_vector_type(4))) float floatx4;

__device__ __forceinline__ ushort_t f2bf(float f) {
  union { float f; unsigned int u; } x; x.f = f;
  unsigned int r = (x.u + 0x7FFFu + ((x.u >> 16) & 1u)) >> 16;  // RNE
  return (ushort_t)r;
}
__device__ __forceinline__ float bf2f(ushort_t u) {
  union { unsigned int u; float f; } x; x.u = ((unsigned int)u) << 16;
  return x.f;
}

// sense-reversing grid barrier; gen polled with read-only atomic loads.
__device__ __forceinline__ void grid_bar(int* cnt, int* gen) {
  __syncthreads();
  if (threadIdx.x == 0) {
    __threadfence();
    int g = __hip_atomic_load(gen, __ATOMIC_ACQUIRE, __HIP_MEMORY_SCOPE_AGENT);
    if (atomicAdd(cnt, 1) == G_CSR - 1) {
      atomicExch(cnt, 0);                  // reset before release
      __threadfence();
      __hip_atomic_store(gen, g + 1, __ATOMIC_RELEASE, __HIP_MEMORY_SCOPE_AGENT);
    } else {
      while (__hip_atomic_load(gen, __ATOMIC_ACQUIRE,
                               __HIP_MEMORY_SCOPE_AGENT) == g)
        __builtin_amdgcn_s_sleep(8);
    }
    __threadfence();
  }
  __syncthreads();
}

// ---------------- fused preprocessing ----------------
// Wp pack: element (n_global = rowoff+n, k_global = koff+k) at
//   Wp[((gg*(KT/32) + t)*4 + ni)*512 + (qk*16 + lm)*8 + j]
// gg=n>>6, ni=(n>>4)&3, lm=n&15, c=kg>>3, j=kg&7, t=c>>2, qk=c&3.
__device__ __forceinline__ void wp_body(const float* __restrict__ W,
                                        ushort_t* __restrict__ Wp,
                                        int i, int K, int N, int rowoff, int koff,
                                        int KT) {
  if (i < K * N) {
    int n = i / K, k = i - n * K;
    int ng = rowoff + n, kg = koff + k;
    int gg = ng >> 6, ni = (ng >> 4) & 3, lm = ng & 15;
    int c = kg >> 3, j = kg & 7, t = c >> 2, qk = c & 3;
    size_t dst = (((size_t)(gg * (KT / 32) + t) * 4 + ni) * 64 + qk * 16 + lm) * 8 + j;
    Wp[dst] = f2bf(W[(size_t)k * N + n]);
  }
}

// block ranges: [0,5000) cvt_x | [5000,5256) W1l | [5256,5512) W1r
// [5512,6024) W2l | [6024,6536) W2r | [6536,6538) biascat | [6538,9038) deg
#define PREP_BLOCKS 9038
__global__ void prep_kernel(const float* __restrict__ x, ushort_t* __restrict__ xb,
                            const float* __restrict__ W1l, const float* __restrict__ W1r,
                            const float* __restrict__ W2l, const float* __restrict__ W2r,
                            ushort_t* __restrict__ Wp1, ushort_t* __restrict__ Wp2,
                            const float* __restrict__ b2, float* __restrict__ bc,
                            const int* __restrict__ ei, int* __restrict__ deg) {
  int b = blockIdx.x, tid = threadIdx.x;
  if (b < 5000) {
    int i = b * 256 + tid;  // per float4
    const int n4 = (N_NODES * F_IN) / 4;
    if (i < n4) {
      float4 v = ((const float4*)x)[i];
      ushort4 o;
      o.x = f2bf(v.x); o.y = f2bf(v.y); o.z = f2bf(v.z); o.w = f2bf(v.w);
      ((ushort4*)xb)[i] = o;
    }
  } else if (b < 5256) {
    wp_body(W1l, Wp1, (b - 5000) * 256 + tid, 128, 512, 0, 0, 256);
  } else if (b < 5512) {
    wp_body(W1r, Wp1, (b - 5256) * 256 + tid, 128, 512, 0, 128, 256);
  } else if (b < 6024) {
    wp_body(W2l, Wp2, (b - 5512) * 256 + tid, 512, 256, 0, 0, 512);
  } else if (b < 6536) {
    wp_body(W2r, Wp2, (b - 6024) * 256 + tid, 512, 256, 256, 0, 512);
  } else if (b < 6538) {
    int i = (b - 6536) * 256 + tid;
    if (i < 512) bc[i] = (i < 256) ? 0.f : b2[i - 256];
  } else {
    int e = (b - 6538) * 256 + tid;
    if (e < N_EDGES) atomicAdd(&deg[ei[N_EDGES + e]], 1);
  }
}

// ---------------- CSR build (scans + fill), one cooperative kernel ------
__global__ __launch_bounds__(256, 4) void csr_fill_kernel(
    const int* __restrict__ deg, int* __restrict__ bsum, int* __restrict__ boff,
    int* __restrict__ rowptr, int* __restrict__ cursor,
    const int* __restrict__ ei, int* __restrict__ col,
    int* bar_cnt, int* bar_gen) {
  const int bid = blockIdx.x, tid = threadIdx.x;
  __shared__ int sdata[256];
  __shared__ int buf[2][256];

  // ---- phase A: per-tile sums of deg (first 157 blocks) ----
  if (bid < NB_SCAN) {
    int i = bid * 256 + tid;
    sdata[tid] = (i < N_NODES) ? deg[i] : 0;
    __syncthreads();
    #pragma unroll
    for (int off = 128; off > 0; off >>= 1) {
      if (tid < off) sdata[tid] += sdata[tid + off];
      __syncthreads();
    }
    if (tid == 0) bsum[bid] = sdata[0];
  }
  grid_bar(bar_cnt, bar_gen);

  // ---- phase B: exclusive scan of 157 tile sums (block 0) ----
  if (bid == 0) {
    int v = (tid < NB_SCAN) ? bsum[tid] : 0;
    buf[0][tid] = v;
    __syncthreads();
    int cur = 0;
    #pragma unroll
    for (int off = 1; off < 256; off <<= 1) {
      int val = buf[cur][tid];
      if (tid >= off) val += buf[cur][tid - off];
      buf[cur ^ 1][tid] = val;
      __syncthreads();
      cur ^= 1;
    }
    if (tid < NB_SCAN) boff[tid] = buf[cur][tid] - v;  // exclusive
  }
  grid_bar(bar_cnt, bar_gen);

  // ---- phase C: rowptr + cursor (first 157 blocks) ----
  if (bid < NB_SCAN) {
    int i = bid * 256 + tid;
    int v = (i < N_NODES) ? deg[i] : 0;
    buf[0][tid] = v;
    __syncthreads();
    int cur = 0;
    #pragma unroll
    for (int off = 1; off < 256; off <<= 1) {
      int val = buf[cur][tid];
      if (tid >= off) val += buf[cur][tid - off];
      buf[cur ^ 1][tid] = val;
      __syncthreads();
      cur ^= 1;
    }
    if (i < N_NODES) {
      int ex = boff[bid] + buf[cur][tid] - v;
      rowptr[i] = ex;
      cursor[i] = ex;
      if (i == N_NODES - 1) rowptr[N_NODES] = ex + v;  // == E
    }
  }
  grid_bar(bar_cnt, bar_gen);

  // ---- phase D: fill col (all 1024 blocks, grid-stride) ----
  for (int e = bid * 256 + tid; e < N_EDGES; e += G_CSR * 256) {
    int d = ei[N_EDGES + e];
    int s = ei[e];
    int pos = atomicAdd(&cursor[d], 1);
    col[pos] = s;
  }
}

// ---------------- aggregation ----------------
// agg1: 4 nodes per 256-thread block, wave = node (full TLP: 10000 blocks).
__global__ __launch_bounds__(256) void agg1_kernel(
    const ushort_t* __restrict__ Xb, ushort_t* __restrict__ Yb,
    const int* __restrict__ rowptr, const int* __restrict__ colidx) {
  const int wave = threadIdx.x >> 6, lane = threadIdx.x & 63;
  const int n = blockIdx.x * 4 + wave;
  const int s = rowptr[n], e = rowptr[n + 1];
  float s0 = 0.f, s1 = 0.f;
  for (int base = s; base < e; base += 64) {
    int cnt = min(64, e - base);
    int c = (base + lane < e) ? colidx[base + lane] : 0;  // coalesced
    int j = 0;
    for (; j + 8 <= cnt; j += 8) {
      unsigned int v[8];
      #pragma unroll
      for (int u = 0; u < 8; ++u) {
        int col = __builtin_amdgcn_readlane(c, j + u);
        v[u] = *(const unsigned int*)(Xb + (size_t)col * F_IN + 2 * lane);
      }
      #pragma unroll
      for (int u = 0; u < 8; ++u) {
        s0 += bf2f((ushort_t)(v[u] & 0xffffu));
        s1 += bf2f((ushort_t)(v[u] >> 16));
      }
    }
    for (; j < cnt; ++j) {
      int col = __builtin_amdgcn_readlane(c, j);
      unsigned int v = *(const unsigned int*)(Xb + (size_t)col * F_IN + 2 * lane);
      s0 += bf2f((ushort_t)(v & 0xffffu));
      s1 += bf2f((ushort_t)(v >> 16));
    }
  }
  float inv = 1.f / fmaxf((float)(e - s), 1.f);
  unsigned int o = (unsigned int)f2bf(s0 * inv) | ((unsigned int)f2bf(s1 * inv) << 16);
  *(unsigned int*)(Yb + (size_t)n * F_IN + 2 * lane) = o;
}

__global__ void agg2_kernel(const ushort_t* __restrict__ hl, const float* __restrict__ hr,
                            float* __restrict__ out,
                            const int* __restrict__ rowptr, const int* __restrict__ colidx) {
  __shared__ int cols[128];
  int n = blockIdx.x, f = threadIdx.x;
  int s = rowptr[n], e = rowptr[n + 1];
  float2 hrv = *(const float2*)(hr + (size_t)n * F_OUT + 2 * f);  // hoisted stream
  float s0 = 0.f, s1 = 0.f;
  for (int base = s; base < e; base += 128) {
    int cnt = min(128, e - base);
    __syncthreads();
    if (f < cnt) cols[f] = colidx[base + f];
    __syncthreads();
    int j = 0;
    for (; j + 8 <= cnt; j += 8) {  // 8 gathers in flight
      unsigned int v[8];
      #pragma unroll
      for (int u = 0; u < 8; ++u)
        v[u] = *(const unsigned int*)(hl + (size_t)cols[j + u] * F_OUT + 2 * f);
      #pragma unroll
      for (int u = 0; u < 8; ++u) {
        s0 += bf2f((ushort_t)(v[u] & 0xffffu));
        s1 += bf2f((ushort_t)(v[u] >> 16));
      }
    }
    for (; j < cnt; ++j) {
      unsigned int v = *(const unsigned int*)(hl + (size_t)cols[j] * F_OUT + 2 * f);
      s0 += bf2f((ushort_t)(v & 0xffffu));
      s1 += bf2f((ushort_t)(v >> 16));
    }
  }
  float inv = 1.f / fmaxf((float)(e - s), 1.f);
  float2 o;
  o.x = s0 * inv + hrv.x;
  o.y = s1 * inv + hrv.y;
  *(float2*)(out + (size_t)n * F_OUT + 2 * f) = o;
}

// ---------------- fused two-layer bf16 MFMA GEMM, BM=64, aliased LDS ----
// (round-17 kernel, unchanged) Per 64-row M-tile (grid 625, 512 thr/8 waves,
// wave w owns cols w*64..w*64+63): stage [aggx|x] -> Pan (swizzled);
// K-loop1 (KT=256) -> acc1; barrier; relu+bias -> bf16 -> Pan; barrier;
// K-loop2 (KT=512, A=Pan) -> acc2; split epilogue. LDS 64 KB aliased.
__device__ __forceinline__ void mm64(const ushort_t* Pan, int k, int qk, int lm,
                                     bf16x8 f0, bf16x8 f1, bf16x8 f2, bf16x8 f3,
                                     floatx4 (&acc)[4][4]) {
  const int kc = k / 8 + qk;
  #pragma unroll
  for (int mi = 0; mi < 4; ++mi) {
    size_t o = ((size_t)(kc * 64 + mi * 16 + lm) * 16) ^ (size_t)((kc & 7) << 4);
    bf16x8 av = *(const bf16x8*)((const char*)Pan + o);
    acc[mi][0] = __builtin_amdgcn_mfma_f32_16x16x32_bf16(f0, av, acc[mi][0], 0, 0, 0);
    acc[mi][1] = __builtin_amdgcn_mfma_f32_16x16x32_bf16(f1, av, acc[mi][1], 0, 0, 0);
    acc[mi][2] = __builtin_amdgcn_mfma_f32_16x16x32_bf16(f2, av, acc[mi][2], 0, 0, 0);
    acc[mi][3] = __builtin_amdgcn_mfma_f32_16x16x32_bf16(f3, av, acc[mi][3], 0, 0, 0);
  }
}

__global__ __launch_bounds__(512) void gemm_fused(
    const ushort_t* __restrict__ A0,   // aggx  [40000][128]
    const ushort_t* __restrict__ A1,   // x     [40000][128]
    const ushort_t* __restrict__ Wp1,  // packed layer-1 weights (KT=256)
    const float* __restrict__ b1,
    const ushort_t* __restrict__ Wp2,  // packed layer-2 weights (KT=512)
    const float* __restrict__ bc,      // [0 | b2]
    float* __restrict__ hr, ushort_t* __restrict__ hl) {
  __shared__ ushort_t Pan[64 * 512];   // 64 KB: A panel (first 32 KB), then H
  const int tid = threadIdx.x;
  const int wave = tid >> 6, lane = tid & 63;
  const int lm = lane & 15, qk = lane >> 4;
  const int bm = blockIdx.x * 64;      // 625 * 64 = 40000, no tail

  const ushort_t* wpg1 = Wp1 + (size_t)wave * 8 * 2048;   // (256/32) t-blocks
  const ushort_t* wpg2 = Wp2 + (size_t)wave * 16 * 2048;  // (512/32) t-blocks
#define LDB1(t, ni) (*(const bf16x8*)(wpg1 + ((size_t)(t) * 4 + (ni)) * 512 + lane * 8))
#define LDB2(t, ni) (*(const bf16x8*)(wpg2 + ((size_t)(t) * 4 + (ni)) * 512 + lane * 8))

  // ---- stage [aggx|x] panel: 64 rows x 32 chunks, 4 chunks per thread ----
  #pragma unroll
  for (int q = 0; q < 4; ++q) {
    int c = tid + q * 512;
    int lc = c & 31;              // chunk (k / 8)
    int row = c >> 5;             // 0..63
    const ushort_t* src = (lc >= 16)
        ? A1 + (size_t)(bm + row) * 128 + (lc - 16) * 8
        : A0 + (size_t)(bm + row) * 128 + lc * 8;
    bf16x8 v = *(const bf16x8*)src;
    size_t off = ((size_t)(lc * 64 + row) * 16) ^ (size_t)((lc & 7) << 4);
    *(bf16x8*)((char*)Pan + off) = v;
  }

  bf16x8 bvA[4], bvB[4];
  #pragma unroll
  for (int ni = 0; ni < 4; ++ni) bvA[ni] = LDB1(0, ni);
  __syncthreads();  // barrier 1: A panel visible

  // ---- K-loop 1 (KT = 256) ----
  floatx4 acc1[4][4] = {};
  #pragma unroll 1
  for (int kb = 0; kb < 256; kb += 64) {
    const int t0 = kb / 32;
    #pragma unroll
    for (int ni = 0; ni < 4; ++ni) bvB[ni] = LDB1(t0 + 1, ni);
    mm64(Pan, kb, qk, lm, bvA[0], bvA[1], bvA[2], bvA[3], acc1);
    if (kb + 64 < 256) {
      #pragma unroll
      for (int ni = 0; ni < 4; ++ni) bvA[ni] = LDB1(t0 + 2, ni);
    }
    mm64(Pan, kb + 32, qk, lm, bvB[0], bvB[1], bvB[2], bvB[3], acc1);
  }

  #pragma unroll
  for (int ni = 0; ni < 4; ++ni) bvA[ni] = LDB2(0, ni);  // issue before barriers
  __syncthreads();  // barrier 2: all waves done READING A before H overwrites

  // ---- epilogue 1: relu(acc1 + b1) -> bf16 -> Pan (swizzled, full 64 KB) ----
  #pragma unroll
  for (int ni = 0; ni < 4; ++ni) {
    int colg = wave * 64 + ni * 16 + qk * 4;
    float4 b4 = *(const float4*)&b1[colg];
    int lc2 = colg >> 3;
    int sub = (qk & 1) * 8;  // byte offset within the 16-B chunk
    #pragma unroll
    for (int mi = 0; mi < 4; ++mi) {
      int row = mi * 16 + lm;
      ushort4 o;
      o.x = f2bf(fmaxf(acc1[mi][ni][0] + b4.x, 0.f));
      o.y = f2bf(fmaxf(acc1[mi][ni][1] + b4.y, 0.f));
      o.z = f2bf(fmaxf(acc1[mi][ni][2] + b4.z, 0.f));
      o.w = f2bf(fmaxf(acc1[mi][ni][3] + b4.w, 0.f));
      size_t off = (((size_t)(lc2 * 64 + row) * 16) ^ (size_t)((lc2 & 7) << 4)) + sub;
      *(ushort4*)((char*)Pan + off) = o;
    }
  }
  __syncthreads();  // barrier 3: H panel visible

  // ---- K-loop 2 (KT = 512, A = Pan) ----
  floatx4 acc2[4][4] = {};
  #pragma unroll 1
  for (int kb = 0; kb < 512; kb += 64) {
    const int t0 = kb / 32;
    #pragma unroll
    for (int ni = 0; ni < 4; ++ni) bvB[ni] = LDB2(t0 + 1, ni);
    mm64(Pan, kb, qk, lm, bvA[0], bvA[1], bvA[2], bvA[3], acc2);
    if (kb + 64 < 512) {
      #pragma unroll
      for (int ni = 0; ni < 4; ++ni) bvA[ni] = LDB2(t0 + 2, ni);
    }
    mm64(Pan, kb + 32, qk, lm, bvB[0], bvB[1], bvB[2], bvB[3], acc2);
  }
#undef LDB1
#undef LDB2

  // ---- epilogue 2: cols<256 -> hl bf16, cols>=256 -> hr fp32 ----
  #pragma unroll
  for (int ni = 0; ni < 4; ++ni) {
    int colg = wave * 64 + ni * 16 + qk * 4;
    float4 b4 = *(const float4*)&bc[colg];
    #pragma unroll
    for (int mi = 0; mi < 4; ++mi) {
      int rowg = bm + mi * 16 + lm;
      float v0 = acc2[mi][ni][0] + b4.x;
      float v1 = acc2[mi][ni][1] + b4.y;
      float v2 = acc2[mi][ni][2] + b4.z;
      float v3 = acc2[mi][ni][3] + b4.w;
      if (colg < 256) {
        ushort4 o = {f2bf(v0), f2bf(v1), f2bf(v2), f2bf(v3)};
        *(ushort4*)&hl[(size_t)rowg * 256 + colg] = o;
      } else {
        float4 o = {v0, v1, v2, v3};
        *(float4*)&hr[(size_t)rowg * 256 + (colg - 256)] = o;
      }
    }
  }
}

extern "C" void kernel_launch(void* const* d_in, const int* in_sizes, int n_in,
                              void* d_out, int out_size, void* d_ws, size_t ws_size,
                              hipStream_t stream) {
  const float* x = (const float*)d_in[0];
  const int* ei = (const int*)d_in[1];  // int32 per harness, [2][E]
  const float* W1l = (const float*)d_in[2];
  const float* b1 = (const float*)d_in[3];
  const float* W1r = (const float*)d_in[4];
  const float* W2l = (const float*)d_in[5];
  const float* b2 = (const float*)d_in[6];
  const float* W2r = (const float*)d_in[7];
  float* out = (float*)d_out;

  char* ws = (char*)d_ws;
  size_t off = 0;
  auto alloc = [&](size_t bytes) {
    void* p = ws + off;
    off = (off + bytes + 255) & ~(size_t)255;
    return p;
  };
  int* deg = (int*)alloc((size_t)(N_NODES + 64) * 4);  // deg + barrier vars
  int* bar_cnt = deg + N_NODES;      // zeroed together with deg
  int* bar_gen = deg + N_NODES + 1;
  int* rowptr = (int*)alloc((size_t)(N_NODES + 1) * 4);
  int* cursor = (int*)alloc((size_t)N_NODES * 4);
  int* col = (int*)alloc((size_t)N_EDGES * 4);
  int* bsum = (int*)alloc((size_t)NB_SCAN * 4);
  int* boff = (int*)alloc((size_t)NB_SCAN * 4);
  ushort_t* x_bf = (ushort_t*)alloc((size_t)N_NODES * F_IN * 2);
  ushort_t* aggx_bf = (ushort_t*)alloc((size_t)N_NODES * F_IN * 2);
  ushort_t* hl_bf = (ushort_t*)alloc((size_t)N_NODES * F_OUT * 2);  // h@W2l, bf16
  float* hr = (float*)alloc((size_t)N_NODES * F_OUT * 4);           // h@W2r + b2
  ushort_t* Wp1 = (ushort_t*)alloc((size_t)512 * 256 * 2);   // packed [W1l^T|W1r^T]
  ushort_t* Wp2 = (ushort_t*)alloc((size_t)512 * 512 * 2);   // packed [W2l|W2r]
  float* biascat = (float*)alloc(512 * 4);

  // Zero deg + barrier vars in one memset
  hipMemsetAsync(deg, 0, (size_t)(N_NODES + 64) * 4, stream);

  // Fused preprocessing: cvt_x + 4x wp + biascat + deg (independent work)
  prep_kernel<<<PREP_BLOCKS, 256, 0, stream>>>(
      x, x_bf, W1l, W1r, W2l, W2r, Wp1, Wp2, b2, biascat, ei, deg);

  // CSR build (scans + fill) in one cooperative kernel
  csr_fill_kernel<<<G_CSR, 256, 0, stream>>>(
      deg, bsum, boff, rowptr, cursor, ei, col, bar_cnt, bar_gen);

  // Layer-1 aggregation (full TLP), then fused two-layer GEMM
  agg1_kernel<<<N_NODES / 4, 256, 0, stream>>>(x_bf, aggx_bf, rowptr, col);
  gemm_fused<<<625, 512, 0, stream>>>(
      aggx_bf, x_bf, Wp1, b1, Wp2, biascat, hr, hl_bf);
  // out = mean-agg(hl_bf) + hr
  agg2_kernel<<<N_NODES, 128, 0, stream>>>(hl_bf, hr, out, rowptr, col);
}

// Round 14
// 289.755 us; speedup vs baseline: 2.0585x; 1.9966x over previous
//
#include <hip/hip_runtime.h>

// GraphSAGE 2-layer. N=40000, E=640000, 128 -> 512 (relu) -> 256.
// Round 21: revert to round-17 (274.5 us best) + barrier-free scan merge.
// Rounds 19/20 isolated a hard fact: device-atomic grid barriers cost
// ~120 us EACH at 1024 blocks on MI355X (round-20: 3 barriers, zero work,
// 363 us, VALUBusy 0.086%) -- never use software grid sync here again.
// This round's only change vs round-17: scanA/scanB/scanC -> ONE kernel
// with NO sync: block b (of 157) recomputes its own global offset by
// strided-summing deg[0..b*256) (<=156 adds/thread), then scans its tile
// and writes rowptr/cursor. Removes 2 dispatch boundaries + bsum/boff.
// Chain: memset -> prep -> scan1 -> fill -> agg1 -> gemm_fused -> agg2.

#define N_NODES 40000
#define N_EDGES 640000
#define F_IN 128
#define F_HID 512
#define F_OUT 256
#define NB_SCAN 157   // ceil(40000/256)

typedef unsigned short ushort_t;
typedef __attribute__((ext_vector_type(8))) short bf16x8;
typedef __attribute__((ext_vector_type(4))) float floatx4;

__device__ __forceinline__ ushort_t f2bf(float f) {
  union { float f; unsigned int u; } x; x.f = f;
  unsigned int r = (x.u + 0x7FFFu + ((x.u >> 16) & 1u)) >> 16;  // RNE
  return (ushort_t)r;
}
__device__ __forceinline__ float bf2f(ushort_t u) {
  union { unsigned int u; float f; } x; x.u = ((unsigned int)u) << 16;
  return x.f;
}

// ---------------- fused preprocessing ----------------
// Wp pack: element (n_global = rowoff+n, k_global = koff+k) at
//   Wp[((gg*(KT/32) + t)*4 + ni)*512 + (qk*16 + lm)*8 + j]
// gg=n>>6, ni=(n>>4)&3, lm=n&15, c=kg>>3, j=kg&7, t=c>>2, qk=c&3.
__device__ __forceinline__ void wp_body(const float* __restrict__ W,
                                        ushort_t* __restrict__ Wp,
                                        int i, int K, int N, int rowoff, int koff,
                                        int KT) {
  if (i < K * N) {
    int n = i / K, k = i - n * K;
    int ng = rowoff + n, kg = koff + k;
    int gg = ng >> 6, ni = (ng >> 4) & 3, lm = ng & 15;
    int c = kg >> 3, j = kg & 7, t = c >> 2, qk = c & 3;
    size_t dst = (((size_t)(gg * (KT / 32) + t) * 4 + ni) * 64 + qk * 16 + lm) * 8 + j;
    Wp[dst] = f2bf(W[(size_t)k * N + n]);
  }
}

// block ranges: [0,5000) cvt_x | [5000,5256) W1l | [5256,5512) W1r
// [5512,6024) W2l | [6024,6536) W2r | [6536,6538) biascat | [6538,9038) deg
#define PREP_BLOCKS 9038
__global__ void prep_kernel(const float* __restrict__ x, ushort_t* __restrict__ xb,
                            const float* __restrict__ W1l, const float* __restrict__ W1r,
                            const float* __restrict__ W2l, const float* __restrict__ W2r,
                            ushort_t* __restrict__ Wp1, ushort_t* __restrict__ Wp2,
                            const float* __restrict__ b2, float* __restrict__ bc,
                            const int* __restrict__ ei, int* __restrict__ deg) {
  int b = blockIdx.x, tid = threadIdx.x;
  if (b < 5000) {
    int i = b * 256 + tid;  // per float4
    const int n4 = (N_NODES * F_IN) / 4;
    if (i < n4) {
      float4 v = ((const float4*)x)[i];
      ushort4 o;
      o.x = f2bf(v.x); o.y = f2bf(v.y); o.z = f2bf(v.z); o.w = f2bf(v.w);
      ((ushort4*)xb)[i] = o;
    }
  } else if (b < 5256) {
    wp_body(W1l, Wp1, (b - 5000) * 256 + tid, 128, 512, 0, 0, 256);
  } else if (b < 5512) {
    wp_body(W1r, Wp1, (b - 5256) * 256 + tid, 128, 512, 0, 128, 256);
  } else if (b < 6024) {
    wp_body(W2l, Wp2, (b - 5512) * 256 + tid, 512, 256, 0, 0, 512);
  } else if (b < 6536) {
    wp_body(W2r, Wp2, (b - 6024) * 256 + tid, 512, 256, 256, 0, 512);
  } else if (b < 6538) {
    int i = (b - 6536) * 256 + tid;
    if (i < 512) bc[i] = (i < 256) ? 0.f : b2[i - 256];
  } else {
    int e = (b - 6538) * 256 + tid;
    if (e < N_EDGES) atomicAdd(&deg[ei[N_EDGES + e]], 1);
  }
}

// ---------------- CSR scan: one kernel, zero sync ----------------
// Block b: global offset = sum(deg[0..b*256)) computed redundantly
// (strided + LDS reduce), then in-block exclusive scan of its tile.
__global__ __launch_bounds__(256) void scan1_kernel(
    const int* __restrict__ deg, int* __restrict__ rowptr,
    int* __restrict__ cursor) {
  __shared__ int psum[256];
  __shared__ int buf[2][256];
  const int b = blockIdx.x, tid = threadIdx.x;
  const int i = b * 256 + tid;

  // (1) block offset: strided sum over deg[0 .. b*256)
  int partial = 0;
  for (int j = tid; j < b * 256; j += 256) partial += deg[j];
  psum[tid] = partial;
  __syncthreads();
  #pragma unroll
  for (int off = 128; off > 0; off >>= 1) {
    if (tid < off) psum[tid] += psum[tid + off];
    __syncthreads();
  }
  const int blockoff = psum[0];  // broadcast (valid after last barrier)

  // (2) in-block exclusive scan of this tile
  int v = (i < N_NODES) ? deg[i] : 0;
  buf[0][tid] = v;
  __syncthreads();
  int cur = 0;
  #pragma unroll
  for (int off = 1; off < 256; off <<= 1) {
    int val = buf[cur][tid];
    if (tid >= off) val += buf[cur][tid - off];
    buf[cur ^ 1][tid] = val;
    __syncthreads();
    cur ^= 1;
  }
  if (i < N_NODES) {
    int ex = blockoff + buf[cur][tid] - v;
    rowptr[i] = ex;
    cursor[i] = ex;
    if (i == N_NODES - 1) rowptr[N_NODES] = ex + v;  // == E
  }
}

__global__ void fill_kernel(const int* __restrict__ ei, int* __restrict__ cursor,
                            int* __restrict__ col) {
  int e = blockIdx.x * blockDim.x + threadIdx.x;
  if (e < N_EDGES) {
    int d = ei[N_EDGES + e];
    int s = ei[e];
    int pos = atomicAdd(&cursor[d], 1);
    col[pos] = s;
  }
}

// ---------------- aggregation ----------------
// agg1: 4 nodes per 256-thread block, wave = node (full TLP: 10000 blocks).
__global__ __launch_bounds__(256) void agg1_kernel(
    const ushort_t* __restrict__ Xb, ushort_t* __restrict__ Yb,
    const int* __restrict__ rowptr, const int* __restrict__ colidx) {
  const int wave = threadIdx.x >> 6, lane = threadIdx.x & 63;
  const int n = blockIdx.x * 4 + wave;
  const int s = rowptr[n], e = rowptr[n + 1];
  float s0 = 0.f, s1 = 0.f;
  for (int base = s; base < e; base += 64) {
    int cnt = min(64, e - base);
    int c = (base + lane < e) ? colidx[base + lane] : 0;  // coalesced
    int j = 0;
    for (; j + 8 <= cnt; j += 8) {
      unsigned int v[8];
      #pragma unroll
      for (int u = 0; u < 8; ++u) {
        int col = __builtin_amdgcn_readlane(c, j + u);
        v[u] = *(const unsigned int*)(Xb + (size_t)col * F_IN + 2 * lane);
      }
      #pragma unroll
      for (int u = 0; u < 8; ++u) {
        s0 += bf2f((ushort_t)(v[u] & 0xffffu));
        s1 += bf2f((ushort_t)(v[u] >> 16));
      }
    }
    for (; j < cnt; ++j) {
      int col = __builtin_amdgcn_readlane(c, j);
      unsigned int v = *(const unsigned int*)(Xb + (size_t)col * F_IN + 2 * lane);
      s0 += bf2f((ushort_t)(v & 0xffffu));
      s1 += bf2f((ushort_t)(v >> 16));
    }
  }
  float inv = 1.f / fmaxf((float)(e - s), 1.f);
  unsigned int o = (unsigned int)f2bf(s0 * inv) | ((unsigned int)f2bf(s1 * inv) << 16);
  *(unsigned int*)(Yb + (size_t)n * F_IN + 2 * lane) = o;
}

__global__ void agg2_kernel(const ushort_t* __restrict__ hl, const float* __restrict__ hr,
                            float* __restrict__ out,
                            const int* __restrict__ rowptr, const int* __restrict__ colidx) {
  __shared__ int cols[128];
  int n = blockIdx.x, f = threadIdx.x;
  int s = rowptr[n], e = rowptr[n + 1];
  float2 hrv = *(const float2*)(hr + (size_t)n * F_OUT + 2 * f);  // hoisted stream
  float s0 = 0.f, s1 = 0.f;
  for (int base = s; base < e; base += 128) {
    int cnt = min(128, e - base);
    __syncthreads();
    if (f < cnt) cols[f] = colidx[base + f];
    __syncthreads();
    int j = 0;
    for (; j + 8 <= cnt; j += 8) {  // 8 gathers in flight
      unsigned int v[8];
      #pragma unroll
      for (int u = 0; u < 8; ++u)
        v[u] = *(const unsigned int*)(hl + (size_t)cols[j + u] * F_OUT + 2 * f);
      #pragma unroll
      for (int u = 0; u < 8; ++u) {
        s0 += bf2f((ushort_t)(v[u] & 0xffffu));
        s1 += bf2f((ushort_t)(v[u] >> 16));
      }
    }
    for (; j < cnt; ++j) {
      unsigned int v = *(const unsigned int*)(hl + (size_t)cols[j] * F_OUT + 2 * f);
      s0 += bf2f((ushort_t)(v & 0xffffu));
      s1 += bf2f((ushort_t)(v >> 16));
    }
  }
  float inv = 1.f / fmaxf((float)(e - s), 1.f);
  float2 o;
  o.x = s0 * inv + hrv.x;
  o.y = s1 * inv + hrv.y;
  *(float2*)(out + (size_t)n * F_OUT + 2 * f) = o;
}

// ---------------- fused two-layer bf16 MFMA GEMM, BM=64, aliased LDS ----
// (round-17 kernel, unchanged) Per 64-row M-tile (grid 625, 512 thr/8 waves,
// wave w owns cols w*64..w*64+63): stage [aggx|x] -> Pan (swizzled);
// K-loop1 (KT=256) -> acc1; barrier; relu+bias -> bf16 -> Pan; barrier;
// K-loop2 (KT=512, A=Pan) -> acc2; split epilogue. LDS 64 KB aliased.
__device__ __forceinline__ void mm64(const ushort_t* Pan, int k, int qk, int lm,
                                     bf16x8 f0, bf16x8 f1, bf16x8 f2, bf16x8 f3,
                                     floatx4 (&acc)[4][4]) {
  const int kc = k / 8 + qk;
  #pragma unroll
  for (int mi = 0; mi < 4; ++mi) {
    size_t o = ((size_t)(kc * 64 + mi * 16 + lm) * 16) ^ (size_t)((kc & 7) << 4);
    bf16x8 av = *(const bf16x8*)((const char*)Pan + o);
    acc[mi][0] = __builtin_amdgcn_mfma_f32_16x16x32_bf16(f0, av, acc[mi][0], 0, 0, 0);
    acc[mi][1] = __builtin_amdgcn_mfma_f32_16x16x32_bf16(f1, av, acc[mi][1], 0, 0, 0);
    acc[mi][2] = __builtin_amdgcn_mfma_f32_16x16x32_bf16(f2, av, acc[mi][2], 0, 0, 0);
    acc[mi][3] = __builtin_amdgcn_mfma_f32_16x16x32_bf16(f3, av, acc[mi][3], 0, 0, 0);
  }
}

__global__ __launch_bounds__(512) void gemm_fused(
    const ushort_t* __restrict__ A0,   // aggx  [40000][128]
    const ushort_t* __restrict__ A1,   // x     [40000][128]
    const ushort_t* __restrict__ Wp1,  // packed layer-1 weights (KT=256)
    const float* __restrict__ b1,
    const ushort_t* __restrict__ Wp2,  // packed layer-2 weights (KT=512)
    const float* __restrict__ bc,      // [0 | b2]
    float* __restrict__ hr, ushort_t* __restrict__ hl) {
  __shared__ ushort_t Pan[64 * 512];   // 64 KB: A panel (first 32 KB), then H
  const int tid = threadIdx.x;
  const int wave = tid >> 6, lane = tid & 63;
  const int lm = lane & 15, qk = lane >> 4;
  const int bm = blockIdx.x * 64;      // 625 * 64 = 40000, no tail

  const ushort_t* wpg1 = Wp1 + (size_t)wave * 8 * 2048;   // (256/32) t-blocks
  const ushort_t* wpg2 = Wp2 + (size_t)wave * 16 * 2048;  // (512/32) t-blocks
#define LDB1(t, ni) (*(const bf16x8*)(wpg1 + ((size_t)(t) * 4 + (ni)) * 512 + lane * 8))
#define LDB2(t, ni) (*(const bf16x8*)(wpg2 + ((size_t)(t) * 4 + (ni)) * 512 + lane * 8))

  // ---- stage [aggx|x] panel: 64 rows x 32 chunks, 4 chunks per thread ----
  #pragma unroll
  for (int q = 0; q < 4; ++q) {
    int c = tid + q * 512;
    int lc = c & 31;              // chunk (k / 8)
    int row = c >> 5;             // 0..63
    const ushort_t* src = (lc >= 16)
        ? A1 + (size_t)(bm + row) * 128 + (lc - 16) * 8
        : A0 + (size_t)(bm + row) * 128 + lc * 8;
    bf16x8 v = *(const bf16x8*)src;
    size_t off = ((size_t)(lc * 64 + row) * 16) ^ (size_t)((lc & 7) << 4);
    *(bf16x8*)((char*)Pan + off) = v;
  }

  bf16x8 bvA[4], bvB[4];
  #pragma unroll
  for (int ni = 0; ni < 4; ++ni) bvA[ni] = LDB1(0, ni);
  __syncthreads();  // barrier 1: A panel visible

  // ---- K-loop 1 (KT = 256) ----
  floatx4 acc1[4][4] = {};
  #pragma unroll 1
  for (int kb = 0; kb < 256; kb += 64) {
    const int t0 = kb / 32;
    #pragma unroll
    for (int ni = 0; ni < 4; ++ni) bvB[ni] = LDB1(t0 + 1, ni);
    mm64(Pan, kb, qk, lm, bvA[0], bvA[1], bvA[2], bvA[3], acc1);
    if (kb + 64 < 256) {
      #pragma unroll
      for (int ni = 0; ni < 4; ++ni) bvA[ni] = LDB1(t0 + 2, ni);
    }
    mm64(Pan, kb + 32, qk, lm, bvB[0], bvB[1], bvB[2], bvB[3], acc1);
  }

  #pragma unroll
  for (int ni = 0; ni < 4; ++ni) bvA[ni] = LDB2(0, ni);  // issue before barriers
  __syncthreads();  // barrier 2: all waves done READING A before H overwrites

  // ---- epilogue 1: relu(acc1 + b1) -> bf16 -> Pan (swizzled, full 64 KB) ----
  #pragma unroll
  for (int ni = 0; ni < 4; ++ni) {
    int colg = wave * 64 + ni * 16 + qk * 4;
    float4 b4 = *(const float4*)&b1[colg];
    int lc2 = colg >> 3;
    int sub = (qk & 1) * 8;  // byte offset within the 16-B chunk
    #pragma unroll
    for (int mi = 0; mi < 4; ++mi) {
      int row = mi * 16 + lm;
      ushort4 o;
      o.x = f2bf(fmaxf(acc1[mi][ni][0] + b4.x, 0.f));
      o.y = f2bf(fmaxf(acc1[mi][ni][1] + b4.y, 0.f));
      o.z = f2bf(fmaxf(acc1[mi][ni][2] + b4.z, 0.f));
      o.w = f2bf(fmaxf(acc1[mi][ni][3] + b4.w, 0.f));
      size_t off = (((size_t)(lc2 * 64 + row) * 16) ^ (size_t)((lc2 & 7) << 4)) + sub;
      *(ushort4*)((char*)Pan + off) = o;
    }
  }
  __syncthreads();  // barrier 3: H panel visible

  // ---- K-loop 2 (KT = 512, A = Pan) ----
  floatx4 acc2[4][4] = {};
  #pragma unroll 1
  for (int kb = 0; kb < 512; kb += 64) {
    const int t0 = kb / 32;
    #pragma unroll
    for (int ni = 0; ni < 4; ++ni) bvB[ni] = LDB2(t0 + 1, ni);
    mm64(Pan, kb, qk, lm, bvA[0], bvA[1], bvA[2], bvA[3], acc2);
    if (kb + 64 < 512) {
      #pragma unroll
      for (int ni = 0; ni < 4; ++ni) bvA[ni] = LDB2(t0 + 2, ni);
    }
    mm64(Pan, kb + 32, qk, lm, bvB[0], bvB[1], bvB[2], bvB[3], acc2);
  }
#undef LDB1
#undef LDB2

  // ---- epilogue 2: cols<256 -> hl bf16, cols>=256 -> hr fp32 ----
  #pragma unroll
  for (int ni = 0; ni < 4; ++ni) {
    int colg = wave * 64 + ni * 16 + qk * 4;
    float4 b4 = *(const float4*)&bc[colg];
    #pragma unroll
    for (int mi = 0; mi < 4; ++mi) {
      int rowg = bm + mi * 16 + lm;
      float v0 = acc2[mi][ni][0] + b4.x;
      float v1 = acc2[mi][ni][1] + b4.y;
      float v2 = acc2[mi][ni][2] + b4.z;
      float v3 = acc2[mi][ni][3] + b4.w;
      if (colg < 256) {
        ushort4 o = {f2bf(v0), f2bf(v1), f2bf(v2), f2bf(v3)};
        *(ushort4*)&hl[(size_t)rowg * 256 + colg] = o;
      } else {
        float4 o = {v0, v1, v2, v3};
        *(float4*)&hr[(size_t)rowg * 256 + (colg - 256)] = o;
      }
    }
  }
}

extern "C" void kernel_launch(void* const* d_in, const int* in_sizes, int n_in,
                              void* d_out, int out_size, void* d_ws, size_t ws_size,
                              hipStream_t stream) {
  const float* x = (const float*)d_in[0];
  const int* ei = (const int*)d_in[1];  // int32 per harness, [2][E]
  const float* W1l = (const float*)d_in[2];
  const float* b1 = (const float*)d_in[3];
  const float* W1r = (const float*)d_in[4];
  const float* W2l = (const float*)d_in[5];
  const float* b2 = (const float*)d_in[6];
  const float* W2r = (const float*)d_in[7];
  float* out = (float*)d_out;

  char* ws = (char*)d_ws;
  size_t off = 0;
  auto alloc = [&](size_t bytes) {
    void* p = ws + off;
    off = (off + bytes + 255) & ~(size_t)255;
    return p;
  };
  int* deg = (int*)alloc((size_t)N_NODES * 4);
  int* rowptr = (int*)alloc((size_t)(N_NODES + 1) * 4);
  int* cursor = (int*)alloc((size_t)N_NODES * 4);
  int* col = (int*)alloc((size_t)N_EDGES * 4);
  ushort_t* x_bf = (ushort_t*)alloc((size_t)N_NODES * F_IN * 2);
  ushort_t* aggx_bf = (ushort_t*)alloc((size_t)N_NODES * F_IN * 2);
  ushort_t* hl_bf = (ushort_t*)alloc((size_t)N_NODES * F_OUT * 2);  // h@W2l, bf16
  float* hr = (float*)alloc((size_t)N_NODES * F_OUT * 4);           // h@W2r + b2
  ushort_t* Wp1 = (ushort_t*)alloc((size_t)512 * 256 * 2);   // packed [W1l^T|W1r^T]
  ushort_t* Wp2 = (ushort_t*)alloc((size_t)512 * 512 * 2);   // packed [W2l|W2r]
  float* biascat = (float*)alloc(512 * 4);

  // Zero deg
  hipMemsetAsync(deg, 0, (size_t)N_NODES * 4, stream);

  // Fused preprocessing: cvt_x + 4x wp + biascat + deg (independent work)
  prep_kernel<<<PREP_BLOCKS, 256, 0, stream>>>(
      x, x_bf, W1l, W1r, W2l, W2r, Wp1, Wp2, b2, biascat, ei, deg);

  // CSR: one barrier-free scan kernel, then fill
  scan1_kernel<<<NB_SCAN, 256, 0, stream>>>(deg, rowptr, cursor);
  fill_kernel<<<(N_EDGES + 255) / 256, 256, 0, stream>>>(ei, cursor, col);

  // Layer-1 aggregation (full TLP), then fused two-layer GEMM
  agg1_kernel<<<N_NODES / 4, 256, 0, stream>>>(x_bf, aggx_bf, rowptr, col);
  gemm_fused<<<625, 512, 0, stream>>>(
      aggx_bf, x_bf, Wp1, b1, Wp2, biascat, hr, hl_bf);
  // out = mean-agg(hl_bf) + hr
  agg2_kernel<<<N_NODES, 128, 0, stream>>>(hl_bf, hr, out, rowptr, col);
}